// Round 3
// baseline (1112.163 us; speedup 1.0000x reference)
//
#include <hip/hip_runtime.h>

#define B_SZ 256
#define L_SZ 512
#define D_SZ 1024

// ---------------------------------------------------------------------------
// Kernel 2: fused scores + online softmax + weighted context + h assembly.
// One 1024-thread block (16 waves) per batch. Each wave processes rows
// l = wave, wave+16, ... with a single pass over contextF/contextR (read-once,
// memory-roofline). Raw scores kept in LDS; attn outputs normalized at end.
// ---------------------------------------------------------------------------
__global__ __launch_bounds__(1024) void attn_fused_kernel(
    const float* __restrict__ cF, const float* __restrict__ cR,
    const float* __restrict__ target, const float* __restrict__ input,
    float* __restrict__ h, float* __restrict__ attnF, float* __restrict__ attnR)
{
    const int b = blockIdx.x;
    const int tid = threadIdx.x;
    const int lane = tid & 63;
    const int wave = tid >> 6;  // 0..15

    __shared__ float s_sF[L_SZ];
    __shared__ float s_sR[L_SZ];
    __shared__ float s_accF[D_SZ];
    __shared__ float s_accR[D_SZ];
    __shared__ float s_mF[16], s_zF[16], s_mR[16], s_zR[16];

    s_accF[tid] = 0.f;
    s_accR[tid] = 0.f;

    // target fragment: lane owns dims d = k*256 + lane*4 + j  (k=0..3, j=0..3)
    float tF[16];
    const float* tb = target + b * D_SZ;
#pragma unroll
    for (int k = 0; k < 4; ++k) {
        float4 v = *reinterpret_cast<const float4*>(&tb[k * 256 + lane * 4]);
        tF[k*4+0] = v.x; tF[k*4+1] = v.y; tF[k*4+2] = v.z; tF[k*4+3] = v.w;
    }

    const float* cFb = cF + (size_t)b * L_SZ * D_SZ;
    const float* cRb = cR + (size_t)b * L_SZ * D_SZ;

    float accF[16], accR[16];
#pragma unroll
    for (int j = 0; j < 16; ++j) { accF[j] = 0.f; accR[j] = 0.f; }
    float mF = -1e30f, zF = 0.f, mR = -1e30f, zR = 0.f;

    for (int l = wave; l < L_SZ; l += 16) {
        const float* rF = cFb + l * D_SZ;
        const float* rR = cRb + l * D_SZ;
        float vF[16], vR[16];
#pragma unroll
        for (int k = 0; k < 4; ++k) {
            float4 a = *reinterpret_cast<const float4*>(&rF[k * 256 + lane * 4]);
            vF[k*4+0]=a.x; vF[k*4+1]=a.y; vF[k*4+2]=a.z; vF[k*4+3]=a.w;
            float4 c = *reinterpret_cast<const float4*>(&rR[k * 256 + lane * 4]);
            vR[k*4+0]=c.x; vR[k*4+1]=c.y; vR[k*4+2]=c.z; vR[k*4+3]=c.w;
        }
        float dF = 0.f, dR = 0.f;
#pragma unroll
        for (int j = 0; j < 16; ++j) { dF += vF[j]*tF[j]; dR += vR[j]*tF[j]; }
#pragma unroll
        for (int off = 1; off < 64; off <<= 1) {
            dF += __shfl_xor(dF, off, 64);
            dR += __shfl_xor(dR, off, 64);
        }
        if (lane == 0) { s_sF[l] = dF; s_sR[l] = dR; }

        // online softmax (F) with deferred rescale; condition is wave-uniform
        float p;
        if (dF > mF + 8.f) {
            float r = __expf(mF - dF);
            zF *= r;
#pragma unroll
            for (int j = 0; j < 16; ++j) { accF[j] *= r; accR[j] *= r; }
            mF = dF; p = 1.f;
        } else {
            p = __expf(dF - mF);
        }
        zF += p;
#pragma unroll
        for (int j = 0; j < 16; ++j) { accF[j] += p * vF[j]; accR[j] += p * vR[j]; }

        // R statistics only (attnR output needs max + denom)
        float pR;
        if (dR > mR + 8.f) { zR *= __expf(mR - dR); mR = dR; pR = 1.f; }
        else pR = __expf(dR - mR);
        zR += pR;
    }

    if (lane == 0) { s_mF[wave]=mF; s_zF[wave]=zF; s_mR[wave]=mR; s_zR[wave]=zR; }
    __syncthreads();

    float mFg = -1e30f, mRg = -1e30f;
#pragma unroll
    for (int w = 0; w < 16; ++w) { mFg = fmaxf(mFg, s_mF[w]); mRg = fmaxf(mRg, s_mR[w]); }
    float zFg = 0.f, zRg = 0.f;
#pragma unroll
    for (int w = 0; w < 16; ++w) {
        zFg += s_zF[w] * __expf(s_mF[w] - mFg);
        zRg += s_zR[w] * __expf(s_mR[w] - mRg);
    }

    // merge per-wave accumulators into LDS (scaled to global max)
    const float scF = __expf(mF - mFg);  // wave-uniform
#pragma unroll
    for (int j = 0; j < 16; ++j) {
        int d = (j >> 2) * 256 + lane * 4 + (j & 3);
        atomicAdd(&s_accF[d], accF[j] * scF);
        atomicAdd(&s_accR[d], accR[j] * scF);
    }
    __syncthreads();

    const float invZF = 1.f / zFg;
    const float invZR = 1.f / zRg;

    // h[b] = [weighted_contextF, weighted_contextR (attnF weights!), input]
    {
        const int d = tid;
        float* hb = h + (size_t)b * 3 * D_SZ;
        hb[d]           = s_accF[d] * invZF;
        hb[D_SZ + d]    = s_accR[d] * invZF;
        hb[2*D_SZ + d]  = input[b * D_SZ + d];
    }
    if (tid < L_SZ) {
        attnF[b * L_SZ + tid] = __expf(s_sF[tid] - mFg) * invZF;
        attnR[b * L_SZ + tid] = __expf(s_sR[tid] - mRg) * invZR;
    }
}

// ---------------------------------------------------------------------------
// Split-K fp32 GEMM: C[row,col] += sum_k A[row,k] * B[col,k]   (C = A @ B^T)
// 64x64 tile, 256 threads, 4x4 micro-tile, KC=32 LDS chunks, atomicAdd output.
// C must be pre-zeroed.
// ---------------------------------------------------------------------------
#define TM 64
#define TN 64
#define KC 32

__global__ __launch_bounds__(256) void gemm_atk_kernel(
    const float* __restrict__ A, const float* __restrict__ Bm,
    float* __restrict__ C, int M, int N, int K, int kPerSplit)
{
    __shared__ float As[KC][TM + 4];
    __shared__ float Bs[KC][TN + 4];
    const int tid = threadIdx.x;
    const int row0 = blockIdx.y * TM;
    const int col0 = blockIdx.x * TN;
    const int kbase = blockIdx.z * kPerSplit;

    const int rs = tid >> 3;          // staging row 0..31 (+32)
    const int c4 = (tid & 7) * 4;     // staging k offset 0..28
    const int r0 = (tid >> 4) * 4;    // micro-tile rows
    const int cc0 = (tid & 15) * 4;   // micro-tile cols

    float acc[4][4];
#pragma unroll
    for (int i = 0; i < 4; ++i)
#pragma unroll
        for (int j = 0; j < 4; ++j) acc[i][j] = 0.f;

    for (int kt = 0; kt < kPerSplit; kt += KC) {
        const int k0 = kbase + kt;
#pragma unroll
        for (int i = 0; i < 2; ++i) {
            const int r = rs + i * 32;
            float4 va = *reinterpret_cast<const float4*>(&A[(size_t)(row0 + r) * K + k0 + c4]);
            As[c4+0][r] = va.x; As[c4+1][r] = va.y; As[c4+2][r] = va.z; As[c4+3][r] = va.w;
            float4 vb = *reinterpret_cast<const float4*>(&Bm[(size_t)(col0 + r) * K + k0 + c4]);
            Bs[c4+0][r] = vb.x; Bs[c4+1][r] = vb.y; Bs[c4+2][r] = vb.z; Bs[c4+3][r] = vb.w;
        }
        __syncthreads();
#pragma unroll
        for (int kc = 0; kc < KC; ++kc) {
            float av[4], bv[4];
            *reinterpret_cast<float4*>(av) = *reinterpret_cast<const float4*>(&As[kc][r0]);
            *reinterpret_cast<float4*>(bv) = *reinterpret_cast<const float4*>(&Bs[kc][cc0]);
#pragma unroll
            for (int i = 0; i < 4; ++i)
#pragma unroll
                for (int j = 0; j < 4; ++j) acc[i][j] += av[i] * bv[j];
        }
        __syncthreads();
    }
#pragma unroll
    for (int i = 0; i < 4; ++i)
#pragma unroll
        for (int j = 0; j < 4; ++j)
            atomicAdd(&C[(size_t)(row0 + r0 + i) * N + col0 + cc0 + j], acc[i][j]);
}

__global__ void tanh_kernel(const float* __restrict__ in, float* __restrict__ out, int n)
{
    int i = blockIdx.x * blockDim.x + threadIdx.x;
    if (i < n) out[i] = tanhf(in[i]);
}

// ---------------------------------------------------------------------------
extern "C" void kernel_launch(void* const* d_in, const int* in_sizes, int n_in,
                              void* d_out, int out_size, void* d_ws, size_t ws_size,
                              hipStream_t stream)
{
    const float* input = (const float*)d_in[0];
    const float* cF    = (const float*)d_in[1];
    const float* cR    = (const float*)d_in[2];
    const float* W_in  = (const float*)d_in[3];
    const float* W_out = (const float*)d_in[4];

    float* out     = (float*)d_out;
    float* h_tilde = out;                       // 256*1024
    float* attnF   = out + 262144;              // 256*512
    float* attnR   = out + 262144 + 131072;     // 256*512

    float* ws     = (float*)d_ws;
    float* target = ws;              // 262144 floats (1 MB)
    float* acc3   = ws + 262144;     // 262144 floats (1 MB)
    float* h      = ws + 524288;     // 786432 floats (3 MB)

    // zero the two atomicAdd accumulators (target + acc3)
    hipMemsetAsync(ws, 0, (size_t)524288 * sizeof(float), stream);

    // target = input @ W_in^T   (M=256, N=1024, K=1024, split-K 4)
    gemm_atk_kernel<<<dim3(1024 / TN, 256 / TM, 4), 256, 0, stream>>>(
        input, W_in, target, 256, 1024, 1024, 256);

    // fused attention: scores, softmax, weighted contexts, h assembly
    attn_fused_kernel<<<dim3(B_SZ), dim3(1024), 0, stream>>>(
        cF, cR, target, input, h, attnF, attnR);

    // acc3 = h @ W_out^T   (M=256, N=1024, K=3072, split-K 8)
    gemm_atk_kernel<<<dim3(1024 / TN, 256 / TM, 8), 256, 0, stream>>>(
        h, W_out, acc3, 256, 1024, 3072, 384);

    // h_tilde = tanh(acc3)
    tanh_kernel<<<dim3(262144 / 256), 256, 0, stream>>>(acc3, h_tilde, 262144);
}